// Round 1
// baseline (180.926 us; speedup 1.0000x reference)
//
#include <hip/hip_runtime.h>
#include <hip/hip_bf16.h>

typedef float f32x4 __attribute__((ext_vector_type(4)));
typedef __bf16 bf16x8 __attribute__((ext_vector_type(8)));
typedef __bf16 bf16x4 __attribute__((ext_vector_type(4)));

__device__ __forceinline__ f32x4 mfma16(bf16x8 a, bf16x8 b, f32x4 c) {
    return __builtin_amdgcn_mfma_f32_16x16x32_bf16(a, b, c, 0, 0, 0);
}

__device__ __forceinline__ float redsum16(float v) {
    v += __shfl_xor(v, 1);
    v += __shfl_xor(v, 2);
    v += __shfl_xor(v, 4);
    v += __shfl_xor(v, 8);
    return v;
}

struct bfpair { __bf16 h, l; };
__device__ __forceinline__ bfpair splitf(float f) {
    __bf16 hb = (__bf16)f;
    bfpair p;
    p.h = hb;
    p.l = (__bf16)(f - (float)hb);
    return p;
}

// One block = 64 batch rows. 4 waves; wave wv owns output rows [wv*16, wv*16+16).
// MFMA 16x16x32 frag conventions (m89-verified):
//   A: row = lane&15, k = (lane>>4)*8 + e   (8 contiguous bf16 -> ds_read_b128)
//   B: col = lane&15, k = (lane>>4)*8 + e
//   C: col = lane&15, row = (lane>>4)*4 + reg
__global__ __launch_bounds__(256, 2)
void gated_dqn(const float* __restrict__ x,   const float* __restrict__ hist,
               const float* __restrict__ g1w, const float* __restrict__ g1b,
               const float* __restrict__ g2w, const float* __restrict__ g2b,
               const float* __restrict__ bw,  const float* __restrict__ bb,
               const float* __restrict__ ln1g,const float* __restrict__ ln1b,
               const float* __restrict__ n1w, const float* __restrict__ n1b,
               const float* __restrict__ ln2g,const float* __restrict__ ln2b,
               const float* __restrict__ mw,  const float* __restrict__ mb,
               const float* __restrict__ v1w, const float* __restrict__ v1b,
               const float* __restrict__ v2w, const float* __restrict__ v2b,
               const float* __restrict__ a1w, const float* __restrict__ a1b,
               const float* __restrict__ a2w, const float* __restrict__ a2b,
               float* __restrict__ qout, float* __restrict__ gateout)
{
    // LDS regions (total ~74 KB -> 2 blocks/CU):
    __shared__ __align__(16) __bf16 sXGh[64][136];  // x_gated hi (post-LN1), also features view
    __shared__ __align__(16) __bf16 sXGl[64][136];  // x_gated lo
    __shared__ __align__(16) __bf16 sA1h[64][72];   // staging A hi / f hi
    __shared__ __align__(16) __bf16 sA1l[64][72];   // staging A lo / gate-h / f lo
    __shared__ __align__(16) __bf16 sW[10240];      // weight tiles (multi-view)
    __shared__ float smod[64];

    const int tid = threadIdx.x;
    const int lane = tid & 63;
    const int wv = tid >> 6;
    const int qq = lane >> 4;
    const int c  = lane & 15;
    const int r0 = blockIdx.x * 64;
    const int rb = wv * 16 + qq * 4;   // block-local row base of this lane's C rows

    // ================= Phase 1: h = relu(hist @ g1w^T + g1b)  [64x64, K=2048]
    {
        __bf16 (*Wg)[72] = reinterpret_cast<__bf16 (*)[72]>(sW);
        const int srow = tid >> 4, sc4 = tid & 15;           // 64x64 f32 tile: 16 float4/row
        const float* aSrc = hist + (size_t)(r0 + srow) * 2048 + sc4 * 4;
        const float* wSrc = g1w + (size_t)srow * 2048 + sc4 * 4;
        f32x4 ra[4], rw[4];
        #pragma unroll
        for (int i = 0; i < 4; ++i) {
            ra[i] = *(const f32x4*)(aSrc + i * 16 * 2048);
            rw[i] = *(const f32x4*)(wSrc + i * 16 * 2048);
        }
        f32x4 acc[4] = {{0,0,0,0},{0,0,0,0},{0,0,0,0},{0,0,0,0}};
        for (int kt = 0; kt < 32; ++kt) {
            __syncthreads();                                  // prev MFMAs done reading LDS
            #pragma unroll
            for (int i = 0; i < 4; ++i) {
                bf16x4 va, vw;
                #pragma unroll
                for (int e = 0; e < 4; ++e) { va[e] = (__bf16)ra[i][e]; vw[e] = (__bf16)rw[i][e]; }
                *(bf16x4*)&sA1h[srow + i*16][sc4*4] = va;
                *(bf16x4*)&Wg [srow + i*16][sc4*4] = vw;
            }
            __syncthreads();
            if (kt + 1 < 32) {                                // prefetch next K-tile (hides HBM latency)
                #pragma unroll
                for (int i = 0; i < 4; ++i) {
                    ra[i] = *(const f32x4*)(aSrc + i*16*2048 + (kt+1)*64);
                    rw[i] = *(const f32x4*)(wSrc + i*16*2048 + (kt+1)*64);
                }
            }
            #pragma unroll
            for (int ks = 0; ks < 2; ++ks) {
                bf16x8 a = *(const bf16x8*)&sA1h[wv*16 + c][ks*32 + qq*8];
                #pragma unroll
                for (int n = 0; n < 4; ++n) {
                    bf16x8 b = *(const bf16x8*)&Wg[n*16 + c][ks*32 + qq*8];
                    acc[n] = mfma16(a, b, acc[n]);
                }
            }
        }
        __syncthreads();
        #pragma unroll
        for (int n = 0; n < 4; ++n) {
            float bv = g1b[n*16 + c];
            #pragma unroll
            for (int j = 0; j < 4; ++j)
                sA1l[rb + j][n*16 + c] = (__bf16)fmaxf(acc[n][j] + bv, 0.0f);
        }
    }

    // ================= Phase 2: gate = sigmoid(h @ g2w^T + g2b); mod  [64x32, K=64]
    {
        __bf16 (*Wg2)[72] = reinterpret_cast<__bf16 (*)[72]>(sW);
        const int srow = tid >> 4, sc4 = tid & 15;
        #pragma unroll
        for (int i = 0; i < 2; ++i) {
            f32x4 v = *(const f32x4*)(g2w + (size_t)(srow + i*16) * 64 + sc4 * 4);
            bf16x4 vb;
            #pragma unroll
            for (int e = 0; e < 4; ++e) vb[e] = (__bf16)v[e];
            *(bf16x4*)&Wg2[srow + i*16][sc4*4] = vb;
        }
        __syncthreads();
        f32x4 acc[2] = {{0,0,0,0},{0,0,0,0}};
        #pragma unroll
        for (int ks = 0; ks < 2; ++ks) {
            bf16x8 a = *(const bf16x8*)&sA1l[wv*16 + c][ks*32 + qq*8];
            #pragma unroll
            for (int n = 0; n < 2; ++n) {
                bf16x8 b = *(const bf16x8*)&Wg2[n*16 + c][ks*32 + qq*8];
                acc[n] = mfma16(a, b, acc[n]);
            }
        }
        float s[4] = {0.f, 0.f, 0.f, 0.f};
        #pragma unroll
        for (int n = 0; n < 2; ++n) {
            float bv = g2b[n*16 + c];
            #pragma unroll
            for (int j = 0; j < 4; ++j) {
                float gv = 1.0f / (1.0f + __expf(-(acc[n][j] + bv)));
                gateout[(size_t)(r0 + rb + j) * 32 + n*16 + c] = gv;
                s[j] += gv;
            }
        }
        #pragma unroll
        for (int j = 0; j < 4; ++j) {
            float t = redsum16(s[j]);
            if (c == 0) smod[rb + j] = 0.7f + 0.3f * t * (1.0f / 32.0f);
        }
    }

    // ================= Phase 3: xg = LN1(relu((x @ bw^T)*mod + bb))  [64x128, K=512, hi/lo]
    {
        __bf16 (*Xh)[40] = reinterpret_cast<__bf16 (*)[40]>(&sA1h[0][0]);
        __bf16 (*Xl)[40] = reinterpret_cast<__bf16 (*)[40]>(&sA1l[0][0]);
        __bf16 (*Bh)[40] = reinterpret_cast<__bf16 (*)[40]>(sW);
        __bf16 (*Bl)[40] = reinterpret_cast<__bf16 (*)[40]>(sW + 5120);
        const int srow = tid >> 3, sc3 = tid & 7;             // 32-col f32 tiles: 8 float4/row
        const float* aSrc = x + (size_t)(r0 + srow) * 512 + sc3 * 4;
        const float* wSrc = bw + (size_t)srow * 512 + sc3 * 4;
        f32x4 ra[2], rw[4];
        #pragma unroll
        for (int i = 0; i < 2; ++i) ra[i] = *(const f32x4*)(aSrc + i * 32 * 512);
        #pragma unroll
        for (int i = 0; i < 4; ++i) rw[i] = *(const f32x4*)(wSrc + i * 32 * 512);
        f32x4 acc[8] = {{0,0,0,0},{0,0,0,0},{0,0,0,0},{0,0,0,0},
                        {0,0,0,0},{0,0,0,0},{0,0,0,0},{0,0,0,0}};
        for (int kt = 0; kt < 16; ++kt) {
            __syncthreads();
            #pragma unroll
            for (int i = 0; i < 2; ++i) {
                bf16x4 vh, vl;
                #pragma unroll
                for (int e = 0; e < 4; ++e) { bfpair p = splitf(ra[i][e]); vh[e] = p.h; vl[e] = p.l; }
                *(bf16x4*)&Xh[srow + i*32][sc3*4] = vh;
                *(bf16x4*)&Xl[srow + i*32][sc3*4] = vl;
            }
            #pragma unroll
            for (int i = 0; i < 4; ++i) {
                bf16x4 vh, vl;
                #pragma unroll
                for (int e = 0; e < 4; ++e) { bfpair p = splitf(rw[i][e]); vh[e] = p.h; vl[e] = p.l; }
                *(bf16x4*)&Bh[srow + i*32][sc3*4] = vh;
                *(bf16x4*)&Bl[srow + i*32][sc3*4] = vl;
            }
            __syncthreads();
            if (kt + 1 < 16) {
                #pragma unroll
                for (int i = 0; i < 2; ++i) ra[i] = *(const f32x4*)(aSrc + i*32*512 + (kt+1)*32);
                #pragma unroll
                for (int i = 0; i < 4; ++i) rw[i] = *(const f32x4*)(wSrc + i*32*512 + (kt+1)*32);
            }
            bf16x8 ah = *(const bf16x8*)&Xh[wv*16 + c][qq*8];
            bf16x8 al = *(const bf16x8*)&Xl[wv*16 + c][qq*8];
            #pragma unroll
            for (int n = 0; n < 8; ++n) {
                bf16x8 bh = *(const bf16x8*)&Bh[n*16 + c][qq*8];
                bf16x8 bl = *(const bf16x8*)&Bl[n*16 + c][qq*8];
                acc[n] = mfma16(ah, bh, acc[n]);
                acc[n] = mfma16(al, bh, acc[n]);
                acc[n] = mfma16(ah, bl, acc[n]);
            }
        }
        __syncthreads();
        float mj[4];
        #pragma unroll
        for (int j = 0; j < 4; ++j) mj[j] = smod[rb + j];
        float s[4] = {0,0,0,0}, ss[4] = {0,0,0,0};
        #pragma unroll
        for (int n = 0; n < 8; ++n) {
            float b0 = bb[n*16 + c];
            #pragma unroll
            for (int j = 0; j < 4; ++j) {
                float v = fmaxf(acc[n][j] * mj[j] + b0, 0.0f);
                acc[n][j] = v;
                s[j] += v; ss[j] += v * v;
            }
        }
        float mean[4], rstd[4];
        #pragma unroll
        for (int j = 0; j < 4; ++j) {
            float t  = redsum16(s[j]);
            float t2 = redsum16(ss[j]);
            float m = t * (1.0f/128.0f);
            float var = t2 * (1.0f/128.0f) - m * m;
            mean[j] = m;
            rstd[j] = rsqrtf(var + 1e-5f);
        }
        #pragma unroll
        for (int n = 0; n < 8; ++n) {
            float g = ln1g[n*16 + c], b2 = ln1b[n*16 + c];
            #pragma unroll
            for (int j = 0; j < 4; ++j) {
                float y = (acc[n][j] - mean[j]) * rstd[j] * g + b2;
                bfpair p = splitf(y);
                sXGh[rb + j][n*16 + c] = p.h;
                sXGl[rb + j][n*16 + c] = p.l;
            }
        }
    }

    // ================= Phase 4: f = LN2(relu(xg @ n1w^T + n1b))  [64x64, K=128, hi/lo]
    {
        __bf16 (*Wh)[72] = reinterpret_cast<__bf16 (*)[72]>(sW);
        __bf16 (*Wl)[72] = reinterpret_cast<__bf16 (*)[72]>(sW + 4608);
        const int srow = tid >> 4, sc4 = tid & 15;
        f32x4 acc[4] = {{0,0,0,0},{0,0,0,0},{0,0,0,0},{0,0,0,0}};
        for (int kh = 0; kh < 2; ++kh) {
            __syncthreads();                                  // prev reads of sW / sXG writes ordered
            #pragma unroll
            for (int i = 0; i < 4; ++i) {
                f32x4 v = *(const f32x4*)(n1w + (size_t)(srow + i*16) * 128 + kh*64 + sc4*4);
                bf16x4 vh, vl;
                #pragma unroll
                for (int e = 0; e < 4; ++e) { bfpair p = splitf(v[e]); vh[e] = p.h; vl[e] = p.l; }
                *(bf16x4*)&Wh[srow + i*16][sc4*4] = vh;
                *(bf16x4*)&Wl[srow + i*16][sc4*4] = vl;
            }
            __syncthreads();
            #pragma unroll
            for (int ks = 0; ks < 2; ++ks) {
                bf16x8 ah = *(const bf16x8*)&sXGh[wv*16 + c][kh*64 + ks*32 + qq*8];
                bf16x8 al = *(const bf16x8*)&sXGl[wv*16 + c][kh*64 + ks*32 + qq*8];
                #pragma unroll
                for (int n = 0; n < 4; ++n) {
                    bf16x8 bh = *(const bf16x8*)&Wh[n*16 + c][ks*32 + qq*8];
                    bf16x8 bl = *(const bf16x8*)&Wl[n*16 + c][ks*32 + qq*8];
                    acc[n] = mfma16(ah, bh, acc[n]);
                    acc[n] = mfma16(al, bh, acc[n]);
                    acc[n] = mfma16(ah, bl, acc[n]);
                }
            }
        }
        __syncthreads();
        float s[4] = {0,0,0,0}, ss[4] = {0,0,0,0};
        #pragma unroll
        for (int n = 0; n < 4; ++n) {
            float b0 = n1b[n*16 + c];
            #pragma unroll
            for (int j = 0; j < 4; ++j) {
                float v = fmaxf(acc[n][j] + b0, 0.0f);
                acc[n][j] = v; s[j] += v; ss[j] += v * v;
            }
        }
        #pragma unroll
        for (int j = 0; j < 4; ++j) {
            float t  = redsum16(s[j]);
            float t2 = redsum16(ss[j]);
            float m = t * (1.0f/64.0f);
            float var = t2 * (1.0f/64.0f) - m * m;
            s[j] = m;
            ss[j] = rsqrtf(var + 1e-5f);
        }
        #pragma unroll
        for (int n = 0; n < 4; ++n) {
            float g = ln2g[n*16 + c], b2 = ln2b[n*16 + c];
            #pragma unroll
            for (int j = 0; j < 4; ++j) {
                float y = (acc[n][j] - s[j]) * ss[j] * g + b2;
                bfpair p = splitf(y);
                sA1h[rb + j][n*16 + c] = p.h;
                sA1l[rb + j][n*16 + c] = p.l;
            }
        }
    }

    // ================= Phase 5: features = relu(f @ mw^T + mb)  [64x32, K=64, hi/lo]
    __bf16 (*Fh)[40] = reinterpret_cast<__bf16 (*)[40]>(&sXGh[0][0]);
    __bf16 (*Fl)[40] = reinterpret_cast<__bf16 (*)[40]>(&sXGl[0][0]);
    {
        __bf16 (*Wh)[72] = reinterpret_cast<__bf16 (*)[72]>(sW);
        __bf16 (*Wl)[72] = reinterpret_cast<__bf16 (*)[72]>(sW + 2304);
        const int srow = tid >> 4, sc4 = tid & 15;
        #pragma unroll
        for (int i = 0; i < 2; ++i) {
            f32x4 v = *(const f32x4*)(mw + (size_t)(srow + i*16) * 64 + sc4 * 4);
            bf16x4 vh, vl;
            #pragma unroll
            for (int e = 0; e < 4; ++e) { bfpair p = splitf(v[e]); vh[e] = p.h; vl[e] = p.l; }
            *(bf16x4*)&Wh[srow + i*16][sc4*4] = vh;
            *(bf16x4*)&Wl[srow + i*16][sc4*4] = vl;
        }
        __syncthreads();
        f32x4 acc[2] = {{0,0,0,0},{0,0,0,0}};
        #pragma unroll
        for (int ks = 0; ks < 2; ++ks) {
            bf16x8 ah = *(const bf16x8*)&sA1h[wv*16 + c][ks*32 + qq*8];
            bf16x8 al = *(const bf16x8*)&sA1l[wv*16 + c][ks*32 + qq*8];
            #pragma unroll
            for (int n = 0; n < 2; ++n) {
                bf16x8 bh = *(const bf16x8*)&Wh[n*16 + c][ks*32 + qq*8];
                bf16x8 bl = *(const bf16x8*)&Wl[n*16 + c][ks*32 + qq*8];
                acc[n] = mfma16(ah, bh, acc[n]);
                acc[n] = mfma16(al, bh, acc[n]);
                acc[n] = mfma16(ah, bl, acc[n]);
            }
        }
        #pragma unroll
        for (int n = 0; n < 2; ++n) {
            float b0 = mb[n*16 + c];
            #pragma unroll
            for (int j = 0; j < 4; ++j) {
                float v = fmaxf(acc[n][j] + b0, 0.0f);
                bfpair p = splitf(v);
                Fh[rb + j][n*16 + c] = p.h;
                Fl[rb + j][n*16 + c] = p.l;
            }
        }
    }

    // ================= Phase 6: dueling heads -> q  [K=32, hi/lo]
    {
        __syncthreads();                                      // phase-5 MFMA reads of sW done; F visible
        __bf16 (*V1h)[40] = reinterpret_cast<__bf16 (*)[40]>(sW);
        __bf16 (*V1l)[40] = reinterpret_cast<__bf16 (*)[40]>(sW + 640);
        __bf16 (*A1h)[40] = reinterpret_cast<__bf16 (*)[40]>(sW + 1280);
        __bf16 (*A1l)[40] = reinterpret_cast<__bf16 (*)[40]>(sW + 1920);
        {
            int m   = tid >> 7;          // 0: v1w, 1: a1w
            int row = (tid >> 3) & 15;
            int c4  = tid & 7;
            const float* src = (m == 0 ? v1w : a1w) + row * 32 + c4 * 4;
            f32x4 v = *(const f32x4*)src;
            bf16x4 vh, vl;
            #pragma unroll
            for (int e = 0; e < 4; ++e) { bfpair p = splitf(v[e]); vh[e] = p.h; vl[e] = p.l; }
            __bf16 (*Dh)[40] = (m == 0) ? V1h : A1h;
            __bf16 (*Dl)[40] = (m == 0) ? V1l : A1l;
            *(bf16x4*)&Dh[row][c4*4] = vh;
            *(bf16x4*)&Dl[row][c4*4] = vl;
        }
        __syncthreads();
        bf16x8 ah = *(const bf16x8*)&Fh[wv*16 + c][qq*8];
        bf16x8 al = *(const bf16x8*)&Fl[wv*16 + c][qq*8];
        f32x4 av = {0,0,0,0}, aa = {0,0,0,0};
        {
            bf16x8 bh = *(const bf16x8*)&V1h[c][qq*8];
            bf16x8 bl = *(const bf16x8*)&V1l[c][qq*8];
            av = mfma16(ah, bh, av); av = mfma16(al, bh, av); av = mfma16(ah, bl, av);
        }
        {
            bf16x8 bh = *(const bf16x8*)&A1h[c][qq*8];
            bf16x8 bl = *(const bf16x8*)&A1l[c][qq*8];
            aa = mfma16(ah, bh, aa); aa = mfma16(al, bh, aa); aa = mfma16(ah, bl, aa);
        }
        float v1bc = v1b[c], a1bc = a1b[c], w2 = v2w[c];
        float vb2 = v2b[0];
        float aw0 = a2w[c], aw1 = a2w[16 + c], aw2 = a2w[32 + c], aw3 = a2w[48 + c];
        float ab0 = a2b[0], ab1 = a2b[1], ab2 = a2b[2], ab3 = a2b[3];
        #pragma unroll
        for (int j = 0; j < 4; ++j) {
            float hv = fmaxf(av[j] + v1bc, 0.0f);
            float ha = fmaxf(aa[j] + a1bc, 0.0f);
            float val = redsum16(hv * w2) + vb2;
            float d0 = redsum16(ha * aw0) + ab0;
            float d1 = redsum16(ha * aw1) + ab1;
            float d2 = redsum16(ha * aw2) + ab2;
            float d3 = redsum16(ha * aw3) + ab3;
            float ma = 0.25f * (d0 + d1 + d2 + d3);
            if (c == 0) {
                f32x4 qv = {val + d0 - ma, val + d1 - ma, val + d2 - ma, val + d3 - ma};
                *(f32x4*)(qout + (size_t)(r0 + rb + j) * 4) = qv;
            }
        }
    }
}

extern "C" void kernel_launch(void* const* d_in, const int* in_sizes, int n_in,
                              void* d_out, int out_size, void* d_ws, size_t ws_size,
                              hipStream_t stream) {
    (void)in_sizes; (void)n_in; (void)d_ws; (void)ws_size; (void)out_size;
    const float* x    = (const float*)d_in[0];
    const float* hist = (const float*)d_in[1];
    const float* g1w  = (const float*)d_in[2];
    const float* g1b  = (const float*)d_in[3];
    const float* g2w  = (const float*)d_in[4];
    const float* g2b  = (const float*)d_in[5];
    const float* bw   = (const float*)d_in[6];
    const float* bb   = (const float*)d_in[7];
    const float* ln1g = (const float*)d_in[8];
    const float* ln1b = (const float*)d_in[9];
    const float* n1w  = (const float*)d_in[10];
    const float* n1b  = (const float*)d_in[11];
    const float* ln2g = (const float*)d_in[12];
    const float* ln2b = (const float*)d_in[13];
    const float* mw   = (const float*)d_in[14];
    const float* mb   = (const float*)d_in[15];
    const float* v1w  = (const float*)d_in[16];
    const float* v1b  = (const float*)d_in[17];
    const float* v2w  = (const float*)d_in[18];
    const float* v2b  = (const float*)d_in[19];
    const float* a1w  = (const float*)d_in[20];
    const float* a1b  = (const float*)d_in[21];
    const float* a2w  = (const float*)d_in[22];
    const float* a2b  = (const float*)d_in[23];
    float* qout = (float*)d_out;
    float* gateout = qout + (size_t)65536 * 4;
    gated_dqn<<<dim3(65536 / 64), dim3(256), 0, stream>>>(
        x, hist, g1w, g1b, g2w, g2b, bw, bb, ln1g, ln1b, n1w, n1b,
        ln2g, ln2b, mw, mb, v1w, v1b, v2w, v2b, a1w, a1b, a2w, a2b,
        qout, gateout);
}